// Round 3
// baseline (402.313 us; speedup 1.0000x reference)
//
#include <hip/hip_runtime.h>
#include <hip/hip_bf16.h>

#define HW 131072      // h*w
#define NCH 128        // channels
#define KS 9
#define L_TOTAL 163840 // Q*M*M
#define LPW 16         // l's per wave in main kernel

static __device__ __forceinline__ float bflo(unsigned int p) { return __uint_as_float(p << 16); }
static __device__ __forceinline__ float bfhi(unsigned int p) { return __uint_as_float(p & 0xffff0000u); }
static __device__ __forceinline__ unsigned short f2bf(float f) {
    unsigned int x = __float_as_uint(f);
    return (unsigned short)((x + 0x7fffu + ((x >> 16) & 1u)) >> 16);  // RNE
}
static __device__ __forceinline__ unsigned int pack2(float a, float b) {
    return (unsigned int)f2bf(a) | ((unsigned int)f2bf(b) << 16);
}

// ---------------------------------------------------------------------------
// Kernel A: transpose x[c][p] (fp32) -> xT[p][c] (bf16 pairs): one gather
// index p then reads one contiguous 256B row of 128 channels.
// Grid: HW/128 = 1024 blocks, 256 threads.
// ---------------------------------------------------------------------------
__global__ __launch_bounds__(256) void transpose_x_kernel(
    const float2* __restrict__ xf,        // x: [NCH][HW/2] float2 along p
    unsigned int* __restrict__ xT)        // [HW][NCH/2] uint pairs along c
{
    __shared__ unsigned short tile[128][130];  // [c][p_local]
    const int tid = threadIdx.x;
    const int lane = tid & 63;
    const int wave = tid >> 6;
    const int p0 = blockIdx.x * 128;

    #pragma unroll 8
    for (int it = 0; it < 32; ++it) {
        int c = wave + (it << 2);
        float2 v = xf[(long)c * (HW / 2) + (p0 >> 1) + lane];
        *reinterpret_cast<unsigned int*>(&tile[c][lane * 2]) = pack2(v.x, v.y);
    }
    __syncthreads();
    #pragma unroll 8
    for (int it = 0; it < 32; ++it) {
        int p = wave + (it << 2);
        unsigned short a = tile[2 * lane][p];
        unsigned short b = tile[2 * lane + 1][p];
        xT[(long)(p0 + p) * 64 + lane] = (unsigned int)a | ((unsigned int)b << 16);
    }
}

// ---------------------------------------------------------------------------
// Kernel B: fused gather + channel mean/max + attention + depthwise.
// One wave per l (lane i owns channels 2i,2i+1); block = 64 consecutive l's.
// Pre-BN result written DIRECTLY to d_out in final [q][c][r] fp32 layout via
// an LDS transpose (64 r x 128 c per block). Stats via per-block atomics.
// Grid: L_TOTAL/64 = 2560 blocks, 256 threads.
// ---------------------------------------------------------------------------
__global__ __launch_bounds__(256) void encoder_main_kernel(
    const unsigned int* __restrict__ xT,       // [HW][64]
    const int* __restrict__ cks,               // [L][9]
    const float* __restrict__ att_w,           // [9][2][9]
    const float* __restrict__ att_b,           // [9]
    const float* __restrict__ depth_w,         // [128][9]
    const float* __restrict__ depth_b,         // [128]
    float* __restrict__ out,                   // [Q*NCH][16384] (pre-BN here)
    float* __restrict__ gsum, float* __restrict__ gsq)
{
    __shared__ int   lcks[64 * KS];            // this block's 64x9 indices
    __shared__ float tile[64][129];            // [l_local][c]
    __shared__ float red[4][256];

    const int tid = threadIdx.x;
    const int lane = tid & 63;
    const int wave = tid >> 6;
    const int c0 = lane * 2, c1 = c0 + 1;
    const int base_l = blockIdx.x * 64;

    for (int j = tid; j < 64 * KS; j += 256) lcks[j] = cks[base_l * KS + j];

    // per-lane constants
    float dw0[KS], dw1[KS];
    #pragma unroll
    for (int k = 0; k < KS; ++k) {
        dw0[k] = depth_w[c0 * KS + k];
        dw1[k] = depth_w[c1 * KS + k];
    }
    const float db0 = depth_b[c0], db1 = depth_b[c1];

    float awr[18];
    float abr = 0.0f;
    if (lane < KS) {
        #pragma unroll
        for (int j = 0; j < 18; ++j) awr[j] = att_w[lane * 18 + j];
        abr = att_b[lane];
    } else {
        #pragma unroll
        for (int j = 0; j < 18; ++j) awr[j] = 0.0f;
    }
    __syncthreads();

    float sum0 = 0.f, sum1 = 0.f, sq0 = 0.f, sq1 = 0.f;

    for (int li = 0; li < LPW; ++li) {
        const int l_local = wave * LPW + li;

        float v0[KS], v1[KS];
        #pragma unroll
        for (int k = 0; k < KS; ++k) {
            int idx = lcks[l_local * KS + k];
            unsigned int p = xT[(long)idx * 64 + lane];
            v0[k] = bflo(p);
            v1[k] = bfhi(p);
        }

        // channel sum & max via wave butterfly
        float s[KS], mx[KS];
        #pragma unroll
        for (int k = 0; k < KS; ++k) {
            s[k] = v0[k] + v1[k];
            mx[k] = fmaxf(v0[k], v1[k]);
        }
        #pragma unroll
        for (int st = 1; st < 64; st <<= 1) {
            #pragma unroll
            for (int k = 0; k < KS; ++k) {
                s[k] += __shfl_xor(s[k], st, 64);
                mx[k] = fmaxf(mx[k], __shfl_xor(mx[k], st, 64));
            }
        }

        // attention logits: lane o computes output o; broadcast multipliers
        float att = abr;
        #pragma unroll
        for (int k = 0; k < KS; ++k) {
            att = fmaf(s[k] * 0.0078125f, awr[k], att);   // avg (1/128)
            att = fmaf(mx[k], awr[9 + k], att);           // max
        }
        float mval = 1.0f + 1.0f / (1.0f + __expf(-att)); // 1 + sigmoid
        float mk[KS];
        #pragma unroll
        for (int k = 0; k < KS; ++k) mk[k] = __shfl(mval, k, 64);

        // depthwise projection
        float acc0 = db0, acc1 = db1;
        #pragma unroll
        for (int k = 0; k < KS; ++k) {
            acc0 = fmaf(v0[k] * mk[k], dw0[k], acc0);
            acc1 = fmaf(v1[k] * mk[k], dw1[k], acc1);
        }

        tile[l_local][c0] = acc0;
        tile[l_local][c1] = acc1;

        sum0 += acc0; sum1 += acc1;
        sq0 = fmaf(acc0, acc0, sq0);
        sq1 = fmaf(acc1, acc1, sq1);
    }

    red[0][tid] = sum0;
    red[1][tid] = sum1;
    red[2][tid] = sq0;
    red[3][tid] = sq1;
    __syncthreads();

    // write out: rows are channels, 64 consecutive r per row (256B, coalesced)
    const int q = base_l >> 14;          // /16384
    const int r0 = base_l & 16383;
    #pragma unroll 8
    for (int it = 0; it < 32; ++it) {
        int c = wave + (it << 2);
        out[((long)(q * NCH + c) << 14) + r0 + lane] = tile[lane][c];
    }

    // stats: 4 waves -> 1, then one atomic per (channel, stat)
    const int g = tid >> 6;
    const int i = tid & 63;
    float t = red[g][i] + red[g][64 + i] + red[g][128 + i] + red[g][192 + i];
    float* dst = (g & 2) ? gsq : gsum;
    atomicAdd(&dst[2 * i + (g & 1)], t);
}

// ---------------------------------------------------------------------------
// Kernel C: in-place elementwise BN finalize + SiLU over d_out (fp32).
// Element i -> channel c = (i>>14)&127 (constant within a float4).
// Grid: 20971520/4/256 = 20480 blocks.
// ---------------------------------------------------------------------------
__global__ __launch_bounds__(256) void finalize_kernel(
    float4* __restrict__ out,
    const float* __restrict__ gsum, const float* __restrict__ gsq,
    const float* __restrict__ gamma, const float* __restrict__ beta)
{
    const long i4 = (long)blockIdx.x * 256 + threadIdx.x;
    const int c = (int)(i4 >> 12) & 127;

    const float invN = 1.0f / (float)L_TOTAL;
    const float m = gsum[c] * invN;
    const float var = gsq[c] * invN - m * m;
    const float sc = gamma[c] * rsqrtf(var + 1e-5f);
    const float sh = beta[c] - m * sc;

    float4 v = out[i4];
    float z0 = fmaf(v.x, sc, sh);
    float z1 = fmaf(v.y, sc, sh);
    float z2 = fmaf(v.z, sc, sh);
    float z3 = fmaf(v.w, sc, sh);
    v.x = z0 / (1.0f + __expf(-z0));
    v.y = z1 / (1.0f + __expf(-z1));
    v.z = z2 / (1.0f + __expf(-z2));
    v.w = z3 / (1.0f + __expf(-z3));
    out[i4] = v;
}

extern "C" void kernel_launch(void* const* d_in, const int* in_sizes, int n_in,
                              void* d_out, int out_size, void* d_ws, size_t ws_size,
                              hipStream_t stream) {
    const float2* x_f2 = (const float2*)d_in[0];
    const int* cks     = (const int*)d_in[1];
    const float* aw    = (const float*)d_in[2];
    const float* ab    = (const float*)d_in[3];
    const float* dw    = (const float*)d_in[4];
    const float* db    = (const float*)d_in[5];
    const float* gm    = (const float*)d_in[6];
    const float* bt    = (const float*)d_in[7];
    float* out         = (float*)d_out;

    char* ws = (char*)d_ws;
    unsigned int* xT = (unsigned int*)ws;            // 33,554,432 B
    float* gsum      = (float*)(ws + 33554432);      // 512 B
    float* gsq       = gsum + NCH;                   // 512 B

    hipMemsetAsync(gsum, 0, 2 * NCH * sizeof(float), stream);

    transpose_x_kernel<<<HW / 128, 256, 0, stream>>>(x_f2, xT);
    encoder_main_kernel<<<L_TOTAL / 64, 256, 0, stream>>>(
        xT, cks, aw, ab, dw, db, out, gsum, gsq);
    finalize_kernel<<<out_size / 4 / 256, 256, 0, stream>>>(
        (float4*)out, gsum, gsq, gm, bt);
}

// Round 4
// 320.914 us; speedup vs baseline: 1.2536x; 1.2536x over previous
//
#include <hip/hip_runtime.h>
#include <hip/hip_bf16.h>

#define HW 131072      // h*w
#define NCH 128        // channels
#define KS 9
#define L_TOTAL 163840 // Q*M*M
#define LPW 16         // l's per wave in main kernel

static __device__ __forceinline__ float bflo(unsigned int p) { return __uint_as_float(p << 16); }
static __device__ __forceinline__ float bfhi(unsigned int p) { return __uint_as_float(p & 0xffff0000u); }
static __device__ __forceinline__ unsigned short f2bf(float f) {
    unsigned int x = __float_as_uint(f);
    return (unsigned short)((x + 0x7fffu + ((x >> 16) & 1u)) >> 16);  // RNE
}
static __device__ __forceinline__ unsigned int pack2(float a, float b) {
    return (unsigned int)f2bf(a) | ((unsigned int)f2bf(b) << 16);
}

// ---------------------------------------------------------------------------
// Kernel A: transpose x[c][p] (fp32) -> xT[p][c] (bf16 pairs) AND compute
// per-p channel mean/max (fp32) — the attention inputs depend only on p.
// Grid: HW/128 = 1024 blocks, 256 threads.
// ---------------------------------------------------------------------------
__global__ __launch_bounds__(256) void transpose_x_kernel(
    const float2* __restrict__ xf,        // x: [NCH][HW/2] float2 along p
    unsigned int* __restrict__ xT,        // [HW][NCH/2] uint pairs along c
    float2* __restrict__ meanmaxP)        // [HW] (mean, max) over channels
{
    __shared__ unsigned short tile[128][130];  // [c][p_local]
    __shared__ float ps[4][128];
    __shared__ float pm[4][128];
    const int tid = threadIdx.x;
    const int lane = tid & 63;
    const int wave = tid >> 6;
    const int p0 = blockIdx.x * 128;

    float s0 = 0.f, s1 = 0.f;
    float m0 = -3.4e38f, m1 = -3.4e38f;
    #pragma unroll 8
    for (int it = 0; it < 32; ++it) {
        int c = wave + (it << 2);
        float2 v = xf[(long)c * (HW / 2) + (p0 >> 1) + lane];
        *reinterpret_cast<unsigned int*>(&tile[c][lane * 2]) = pack2(v.x, v.y);
        s0 += v.x; s1 += v.y;
        m0 = fmaxf(m0, v.x); m1 = fmaxf(m1, v.y);
    }
    ps[wave][2 * lane] = s0; ps[wave][2 * lane + 1] = s1;
    pm[wave][2 * lane] = m0; pm[wave][2 * lane + 1] = m1;
    __syncthreads();

    #pragma unroll 8
    for (int it = 0; it < 32; ++it) {
        int p = wave + (it << 2);
        unsigned short a = tile[2 * lane][p];
        unsigned short b = tile[2 * lane + 1][p];
        xT[(long)(p0 + p) * 64 + lane] = (unsigned int)a | ((unsigned int)b << 16);
    }
    if (tid < 128) {
        float s = ps[0][tid] + ps[1][tid] + ps[2][tid] + ps[3][tid];
        float m = fmaxf(fmaxf(pm[0][tid], pm[1][tid]), fmaxf(pm[2][tid], pm[3][tid]));
        meanmaxP[p0 + tid] = make_float2(s * 0.0078125f, m);
    }
}

// ---------------------------------------------------------------------------
// Kernel B: fused gather + attention (from precomputed mean/max) + depthwise.
// Block = 64 consecutive l's. Phase 1: 3 threads per l compute the 9
// attention multipliers (no shuffles). Phase 2: one wave per l, lane i owns
// channels (2i,2i+1): gather + depthwise, write pre-BN result directly to
// d_out in final [q][c][r] layout via an LDS transpose. Stats via atomics.
// Grid: L_TOTAL/64 = 2560 blocks, 256 threads.
// ---------------------------------------------------------------------------
__global__ __launch_bounds__(256) void encoder_main_kernel(
    const unsigned int* __restrict__ xT,       // [HW][64]
    const float2* __restrict__ meanmaxP,       // [HW]
    const int* __restrict__ cks,               // [L][9]
    const float* __restrict__ att_w,           // [9][2][9]
    const float* __restrict__ att_b,           // [9]
    const float* __restrict__ depth_w,         // [128][9]
    const float* __restrict__ depth_b,         // [128]
    float* __restrict__ out,                   // [Q*NCH][16384] (pre-BN)
    float* __restrict__ gsum, float* __restrict__ gsq)
{
    __shared__ __align__(16) char smem[38400];
    float* attw = (float*)smem;                 // 162 floats  [0, 648)
    float* attb = (float*)(smem + 648);         // 9 floats    [648, 684) pad->688
    int*   lcks = (int*)(smem + 688);           // 576 ints    [688, 2992)
    float* mult = (float*)(smem + 2992);        // 576 floats  [2992, 5296) pad->5312
    float* tile = (float*)(smem + 5312);        // 64*129 fl   [5312, 38336)
    float* red  = (float*)smem;                 // 4096 B, aliased (attw/lcks dead)

    const int tid = threadIdx.x;
    const int lane = tid & 63;
    const int wave = tid >> 6;
    const int c0 = lane * 2, c1 = c0 + 1;
    const int base_l = blockIdx.x * 64;

    if (tid < 162) attw[tid] = att_w[tid];
    if (tid < KS) attb[tid] = att_b[tid];
    for (int j = tid; j < 64 * KS; j += 256) lcks[j] = cks[base_l * KS + j];

    float dw0[KS], dw1[KS];
    #pragma unroll
    for (int k = 0; k < KS; ++k) {
        dw0[k] = depth_w[c0 * KS + k];
        dw1[k] = depth_w[c1 * KS + k];
    }
    const float db0 = depth_b[c0], db1 = depth_b[c1];
    __syncthreads();

    // ---- Phase 1: multipliers. thread -> (l_local = tid>>2, sub = tid&3) ----
    {
        const int l_local = tid >> 2;
        const int sub = tid & 3;
        if (sub < 3) {
            float mean[KS], mx[KS];
            #pragma unroll
            for (int k = 0; k < KS; ++k) {
                float2 mm = meanmaxP[lcks[l_local * KS + k]];
                mean[k] = mm.x; mx[k] = mm.y;
            }
            #pragma unroll
            for (int oo = 0; oo < 3; ++oo) {
                int o = sub * 3 + oo;
                float logit = attb[o];
                #pragma unroll
                for (int k = 0; k < KS; ++k) {
                    logit = fmaf(mean[k], attw[o * 18 + k], logit);
                    logit = fmaf(mx[k],   attw[o * 18 + 9 + k], logit);
                }
                mult[l_local * KS + o] = 1.0f + 1.0f / (1.0f + __expf(-logit));
            }
        }
    }
    __syncthreads();

    // ---- Phase 2: gather + depthwise, one wave per l ----
    float sum0 = 0.f, sum1 = 0.f, sq0 = 0.f, sq1 = 0.f;

    for (int li = 0; li < LPW; ++li) {
        const int l_local = wave * LPW + li;
        float acc0 = db0, acc1 = db1;
        #pragma unroll
        for (int k = 0; k < KS; ++k) {
            int idx = __builtin_amdgcn_readfirstlane(lcks[l_local * KS + k]);
            unsigned int p = xT[(long)idx * 64 + lane];
            float mk = mult[l_local * KS + k];
            acc0 = fmaf(bflo(p) * mk, dw0[k], acc0);
            acc1 = fmaf(bfhi(p) * mk, dw1[k], acc1);
        }
        tile[l_local * 129 + c0] = acc0;
        tile[l_local * 129 + c1] = acc1;
        sum0 += acc0; sum1 += acc1;
        sq0 = fmaf(acc0, acc0, sq0);
        sq1 = fmaf(acc1, acc1, sq1);
    }

    __syncthreads();                 // lcks/mult/attw dead; tile complete
    red[0 * 256 + tid] = sum0;
    red[1 * 256 + tid] = sum1;
    red[2 * 256 + tid] = sq0;
    red[3 * 256 + tid] = sq1;
    __syncthreads();

    // write out: rows are channels, 64 consecutive r per row (256B, coalesced)
    const int q = base_l >> 14;
    const int r0 = base_l & 16383;
    #pragma unroll 8
    for (int it = 0; it < 32; ++it) {
        int c = wave + (it << 2);
        out[((long)(q * NCH + c) << 14) + r0 + lane] = tile[lane * 129 + c];
    }

    // stats: 4 waves -> 1, then one atomic per (channel, stat)
    const int g = tid >> 6;
    const int i = tid & 63;
    float t = red[g * 256 + i] + red[g * 256 + 64 + i] +
              red[g * 256 + 128 + i] + red[g * 256 + 192 + i];
    float* dst = (g & 2) ? gsq : gsum;
    atomicAdd(&dst[2 * i + (g & 1)], t);
}

// ---------------------------------------------------------------------------
// Kernel C: in-place elementwise BN finalize + SiLU over d_out (fp32).
// Grid: 20971520/4/256 = 20480 blocks.
// ---------------------------------------------------------------------------
__global__ __launch_bounds__(256) void finalize_kernel(
    float4* __restrict__ out,
    const float* __restrict__ gsum, const float* __restrict__ gsq,
    const float* __restrict__ gamma, const float* __restrict__ beta)
{
    const long i4 = (long)blockIdx.x * 256 + threadIdx.x;
    const int c = (int)(i4 >> 12) & 127;

    const float invN = 1.0f / (float)L_TOTAL;
    const float m = gsum[c] * invN;
    const float var = gsq[c] * invN - m * m;
    const float sc = gamma[c] * rsqrtf(var + 1e-5f);
    const float sh = beta[c] - m * sc;

    float4 v = out[i4];
    float z0 = fmaf(v.x, sc, sh);
    float z1 = fmaf(v.y, sc, sh);
    float z2 = fmaf(v.z, sc, sh);
    float z3 = fmaf(v.w, sc, sh);
    v.x = z0 / (1.0f + __expf(-z0));
    v.y = z1 / (1.0f + __expf(-z1));
    v.z = z2 / (1.0f + __expf(-z2));
    v.w = z3 / (1.0f + __expf(-z3));
    out[i4] = v;
}

extern "C" void kernel_launch(void* const* d_in, const int* in_sizes, int n_in,
                              void* d_out, int out_size, void* d_ws, size_t ws_size,
                              hipStream_t stream) {
    const float2* x_f2 = (const float2*)d_in[0];
    const int* cks     = (const int*)d_in[1];
    const float* aw    = (const float*)d_in[2];
    const float* ab    = (const float*)d_in[3];
    const float* dw    = (const float*)d_in[4];
    const float* db    = (const float*)d_in[5];
    const float* gm    = (const float*)d_in[6];
    const float* bt    = (const float*)d_in[7];
    float* out         = (float*)d_out;

    char* ws = (char*)d_ws;
    unsigned int* xT  = (unsigned int*)ws;               // 33,554,432 B
    float2* meanmaxP  = (float2*)(ws + 33554432);        // 1,048,576 B
    float* gsum       = (float*)(ws + 33554432 + 1048576); // 512 B
    float* gsq        = gsum + NCH;                        // 512 B

    hipMemsetAsync(gsum, 0, 2 * NCH * sizeof(float), stream);

    transpose_x_kernel<<<HW / 128, 256, 0, stream>>>(x_f2, xT, meanmaxP);
    encoder_main_kernel<<<L_TOTAL / 64, 256, 0, stream>>>(
        xT, meanmaxP, cks, aw, ab, dw, db, out, gsum, gsq);
    finalize_kernel<<<out_size / 4 / 256, 256, 0, stream>>>(
        (float4*)out, gsum, gsq, gm, bt);
}

// Round 5
// 320.024 us; speedup vs baseline: 1.2571x; 1.0028x over previous
//
#include <hip/hip_runtime.h>
#include <hip/hip_bf16.h>

#define HW 131072      // h*w
#define NCH 128        // channels
#define KS 9
#define L_TOTAL 163840 // Q*M*M
#define LPW 16         // l's per wave in main kernel

static __device__ __forceinline__ float bflo(unsigned int p) { return __uint_as_float(p << 16); }
static __device__ __forceinline__ float bfhi(unsigned int p) { return __uint_as_float(p & 0xffff0000u); }
static __device__ __forceinline__ unsigned short f2bf(float f) {
    unsigned int x = __float_as_uint(f);
    return (unsigned short)((x + 0x7fffu + ((x >> 16) & 1u)) >> 16);  // RNE
}

// ---------------------------------------------------------------------------
// Kernel A: transpose x[c][p] (fp32) -> xT[p][c] (bf16 pairs) AND per-p
// channel mean/max. LDS tile uses a rotate-swizzle col' = (c + 2p) & 127:
//   - b16 writes: 2-way bank aliasing (free on CDNA4)
//   - transposed reads: one conflict-free ds_read_b32 per output dword
// Grid: HW/128 = 1024 blocks, 256 threads.
// ---------------------------------------------------------------------------
__global__ __launch_bounds__(256) void transpose_x_kernel(
    const float2* __restrict__ xf,        // x: [NCH][HW/2] float2 along p
    unsigned int* __restrict__ xT,        // [HW][NCH/2] uint pairs along c
    float2* __restrict__ meanmaxP)        // [HW] (mean, max) over channels
{
    __shared__ unsigned short tile[128 * 128];  // [p][col'], stride 128
    __shared__ float ps[4][128];
    __shared__ float pm[4][128];
    const int tid = threadIdx.x;
    const int lane = tid & 63;
    const int wave = tid >> 6;
    const int p0 = blockIdx.x * 128;
    const int pa = 2 * lane, pb = 2 * lane + 1;

    float s0 = 0.f, s1 = 0.f;
    float m0 = -3.4e38f, m1 = -3.4e38f;
    #pragma unroll 8
    for (int it = 0; it < 32; ++it) {
        int c = wave + (it << 2);
        float2 v = xf[(long)c * (HW / 2) + (p0 >> 1) + lane];
        tile[pa * 128 + ((c + 2 * pa) & 127)] = f2bf(v.x);
        tile[pb * 128 + ((c + 2 * pb) & 127)] = f2bf(v.y);
        s0 += v.x; s1 += v.y;
        m0 = fmaxf(m0, v.x); m1 = fmaxf(m1, v.y);
    }
    ps[wave][pa] = s0; ps[wave][pb] = s1;
    pm[wave][pa] = m0; pm[wave][pb] = m1;
    __syncthreads();

    #pragma unroll 8
    for (int it = 0; it < 32; ++it) {
        int p = wave + (it << 2);
        int colr = (2 * lane + 2 * p) & 127;          // even -> dword aligned
        unsigned int d = *reinterpret_cast<const unsigned int*>(&tile[p * 128 + colr]);
        xT[(long)(p0 + p) * 64 + lane] = d;
    }
    if (tid < 128) {
        float s = ps[0][tid] + ps[1][tid] + ps[2][tid] + ps[3][tid];
        float m = fmaxf(fmaxf(pm[0][tid], pm[1][tid]), fmaxf(pm[2][tid], pm[3][tid]));
        meanmaxP[p0 + tid] = make_float2(s * 0.0078125f, m);
    }
}

// ---------------------------------------------------------------------------
// Kernel B: fused gather + attention (precomputed mean/max) + depthwise.
// Block = 64 consecutive l's. Phase 1: 3 threads/l compute 9 multipliers.
// Phase 2: one wave per l, lane i owns channels (2i,2i+1); software-pipelined
// gather (all 9 rows of l+1 issued before computing l) for MLP. Pre-BN result
// written directly to d_out in [q][c][r] layout via LDS transpose.
// Grid: L_TOTAL/64 = 2560 blocks, 256 threads.
// ---------------------------------------------------------------------------
__global__ __launch_bounds__(256, 4) void encoder_main_kernel(
    const unsigned int* __restrict__ xT,       // [HW][64]
    const float2* __restrict__ meanmaxP,       // [HW]
    const int* __restrict__ cks,               // [L][9]
    const float* __restrict__ att_w,           // [9][2][9]
    const float* __restrict__ att_b,           // [9]
    const float* __restrict__ depth_w,         // [128][9]
    const float* __restrict__ depth_b,         // [128]
    float* __restrict__ out,                   // [Q*NCH][16384] (pre-BN)
    float* __restrict__ gsum, float* __restrict__ gsq)
{
    __shared__ __align__(16) char smem[38400];
    float* attw = (float*)smem;                 // 162 floats  [0, 648)
    float* attb = (float*)(smem + 648);         // 9 floats    [648, 684) pad->688
    int*   lcks = (int*)(smem + 688);           // 576 ints    [688, 2992)
    float* mult = (float*)(smem + 2992);        // 576 floats  [2992, 5296) pad->5312
    float* tile = (float*)(smem + 5312);        // 64*129 fl   [5312, 38336)
    float* red  = (float*)smem;                 // 4096 B, aliased (dead after ph2)

    const int tid = threadIdx.x;
    const int lane = tid & 63;
    const int wave = tid >> 6;
    const int c0 = lane * 2, c1 = c0 + 1;
    const int base_l = blockIdx.x * 64;

    if (tid < 162) attw[tid] = att_w[tid];
    if (tid < KS) attb[tid] = att_b[tid];
    for (int j = tid; j < 64 * KS; j += 256) lcks[j] = cks[base_l * KS + j];

    float dw0[KS], dw1[KS];
    #pragma unroll
    for (int k = 0; k < KS; ++k) {
        dw0[k] = depth_w[c0 * KS + k];
        dw1[k] = depth_w[c1 * KS + k];
    }
    const float db0 = depth_b[c0], db1 = depth_b[c1];
    __syncthreads();

    // ---- Phase 1: multipliers. thread -> (l_local = tid>>2, sub = tid&3) ----
    {
        const int l_local = tid >> 2;
        const int sub = tid & 3;
        if (sub < 3) {
            float mean[KS], mx[KS];
            #pragma unroll
            for (int k = 0; k < KS; ++k) {
                float2 mm = meanmaxP[lcks[l_local * KS + k]];
                mean[k] = mm.x; mx[k] = mm.y;
            }
            #pragma unroll
            for (int oo = 0; oo < 3; ++oo) {
                int o = sub * 3 + oo;
                float logit = attb[o];
                #pragma unroll
                for (int k = 0; k < KS; ++k) {
                    logit = fmaf(mean[k], attw[o * 18 + k], logit);
                    logit = fmaf(mx[k],   attw[o * 18 + 9 + k], logit);
                }
                mult[l_local * KS + o] = 1.0f + 1.0f / (1.0f + __expf(-logit));
            }
        }
    }
    __syncthreads();

    // ---- Phase 2: software-pipelined gather + depthwise, one wave per l ----
    float sum0 = 0.f, sum1 = 0.f, sq0 = 0.f, sq1 = 0.f;
    const int l0 = wave * LPW;

    unsigned int pv[KS], pn[KS];
    #pragma unroll
    for (int k = 0; k < KS; ++k) {
        int idx = __builtin_amdgcn_readfirstlane(lcks[l0 * KS + k]);
        pv[k] = xT[(long)idx * 64 + lane];
    }

    #pragma unroll
    for (int li = 0; li < LPW; ++li) {
        const int l_local = l0 + li;
        if (li + 1 < LPW) {
            #pragma unroll
            for (int k = 0; k < KS; ++k) {
                int idx = __builtin_amdgcn_readfirstlane(lcks[(l_local + 1) * KS + k]);
                pn[k] = xT[(long)idx * 64 + lane];
            }
        }
        float acc0 = db0, acc1 = db1;
        #pragma unroll
        for (int k = 0; k < KS; ++k) {
            float mk = mult[l_local * KS + k];
            acc0 = fmaf(bflo(pv[k]) * mk, dw0[k], acc0);
            acc1 = fmaf(bfhi(pv[k]) * mk, dw1[k], acc1);
        }
        tile[l_local * 129 + c0] = acc0;
        tile[l_local * 129 + c1] = acc1;
        sum0 += acc0; sum1 += acc1;
        sq0 = fmaf(acc0, acc0, sq0);
        sq1 = fmaf(acc1, acc1, sq1);
        #pragma unroll
        for (int k = 0; k < KS; ++k) pv[k] = pn[k];
    }

    __syncthreads();                 // lcks/mult dead; tile complete
    red[0 * 256 + tid] = sum0;
    red[1 * 256 + tid] = sum1;
    red[2 * 256 + tid] = sq0;
    red[3 * 256 + tid] = sq1;
    __syncthreads();

    // write out: rows are channels, 64 consecutive r per row (256B, coalesced)
    const int q = base_l >> 14;
    const int r0 = base_l & 16383;
    #pragma unroll 8
    for (int it = 0; it < 32; ++it) {
        int c = wave + (it << 2);
        out[((long)(q * NCH + c) << 14) + r0 + lane] = tile[lane * 129 + c];
    }

    // stats: 4 waves -> 1, then one atomic per (channel, stat)
    const int g = tid >> 6;
    const int i = tid & 63;
    float t = red[g * 256 + i] + red[g * 256 + 64 + i] +
              red[g * 256 + 128 + i] + red[g * 256 + 192 + i];
    float* dst = (g & 2) ? gsq : gsum;
    atomicAdd(&dst[2 * i + (g & 1)], t);
}

// ---------------------------------------------------------------------------
// Kernel C: in-place elementwise BN finalize + SiLU over d_out (fp32).
// Grid: 20971520/4/256 = 20480 blocks.
// ---------------------------------------------------------------------------
__global__ __launch_bounds__(256) void finalize_kernel(
    float4* __restrict__ out,
    const float* __restrict__ gsum, const float* __restrict__ gsq,
    const float* __restrict__ gamma, const float* __restrict__ beta)
{
    const long i4 = (long)blockIdx.x * 256 + threadIdx.x;
    const int c = (int)(i4 >> 12) & 127;

    const float invN = 1.0f / (float)L_TOTAL;
    const float m = gsum[c] * invN;
    const float var = gsq[c] * invN - m * m;
    const float sc = gamma[c] * rsqrtf(var + 1e-5f);
    const float sh = beta[c] - m * sc;

    float4 v = out[i4];
    float z0 = fmaf(v.x, sc, sh);
    float z1 = fmaf(v.y, sc, sh);
    float z2 = fmaf(v.z, sc, sh);
    float z3 = fmaf(v.w, sc, sh);
    v.x = z0 / (1.0f + __expf(-z0));
    v.y = z1 / (1.0f + __expf(-z1));
    v.z = z2 / (1.0f + __expf(-z2));
    v.w = z3 / (1.0f + __expf(-z3));
    out[i4] = v;
}

extern "C" void kernel_launch(void* const* d_in, const int* in_sizes, int n_in,
                              void* d_out, int out_size, void* d_ws, size_t ws_size,
                              hipStream_t stream) {
    const float2* x_f2 = (const float2*)d_in[0];
    const int* cks     = (const int*)d_in[1];
    const float* aw    = (const float*)d_in[2];
    const float* ab    = (const float*)d_in[3];
    const float* dw    = (const float*)d_in[4];
    const float* db    = (const float*)d_in[5];
    const float* gm    = (const float*)d_in[6];
    const float* bt    = (const float*)d_in[7];
    float* out         = (float*)d_out;

    char* ws = (char*)d_ws;
    unsigned int* xT  = (unsigned int*)ws;                 // 33,554,432 B
    float2* meanmaxP  = (float2*)(ws + 33554432);          // 1,048,576 B
    float* gsum       = (float*)(ws + 33554432 + 1048576); // 512 B
    float* gsq        = gsum + NCH;                        // 512 B

    hipMemsetAsync(gsum, 0, 2 * NCH * sizeof(float), stream);

    transpose_x_kernel<<<HW / 128, 256, 0, stream>>>(x_f2, xT, meanmaxP);
    encoder_main_kernel<<<L_TOTAL / 64, 256, 0, stream>>>(
        xT, meanmaxP, cks, aw, ab, dw, db, out, gsum, gsq);
    finalize_kernel<<<out_size / 4 / 256, 256, 0, stream>>>(
        (float4*)out, gsum, gsq, gm, bt);
}